// Round 1
// baseline (1995.816 us; speedup 1.0000x reference)
//
#include <hip/hip_runtime.h>
#include <math.h>

typedef unsigned long long u64;

#define N_ANCH 2304
#define NP     2000
#define W1     36   // 2304/64
#define W2     32   // ceil(2048/64) for 2000 boxes

// ---------- output offsets (floats) ----------
#define O_RPN_LOGITS   0
#define O_RPN_DELTAS   4608
#define O_PROPOSALS    13824
#define O_ANCHORS      21824
#define O_RCNN_LOGITS  31040
#define O_RCNN_DELTAS  35040
#define O_RCNN_MASKS   43040
#define O_FINAL_DETS   435040
#define O_FINAL_MASKS  443040
#define O_FINAL_SCORES 835040
#define O_KEEP2        837040

// ============================================================
// K1: backbone 16x16 stride-16 VALID conv + relu -> feat [64,16,16]
// ============================================================
__global__ __launch_bounds__(256) void bb_conv(const float* __restrict__ x,
    const float* __restrict__ w, const float* __restrict__ b, float* __restrict__ feat)
{
    __shared__ float ws_[768];
    int c = blockIdx.x;
    for (int e = threadIdx.x; e < 768; e += 256) ws_[e] = w[c*768 + e];
    __syncthreads();
    int fy = threadIdx.x >> 4, fx = threadIdx.x & 15;
    float acc = b[c];
    for (int ic = 0; ic < 3; ++ic)
        for (int ky = 0; ky < 16; ++ky) {
            const float* xr = x + (size_t)(ic*256 + fy*16+ky)*256 + fx*16;
            const float* wr = ws_ + ic*256 + ky*16;
            #pragma unroll
            for (int kx = 0; kx < 16; ++kx) acc += xr[kx]*wr[kx];
        }
    feat[c*256 + threadIdx.x] = fmaxf(acc, 0.f);
}

// ============================================================
// K2: RPN 3x3 SAME conv + relu -> h [64,16,16]
// ============================================================
__global__ __launch_bounds__(256) void rpn_conv(const float* __restrict__ feat,
    const float* __restrict__ w, const float* __restrict__ b, float* __restrict__ h)
{
    __shared__ float f[16384];
    __shared__ float ws_[576];
    int c = blockIdx.x;
    for (int e = threadIdx.x; e < 16384; e += 256) f[e] = feat[e];
    for (int e = threadIdx.x; e < 576; e += 256) ws_[e] = w[c*576 + e];
    __syncthreads();
    int fy = threadIdx.x >> 4, fx = threadIdx.x & 15;
    float acc = b[c];
    for (int ic = 0; ic < 64; ++ic) {
        const float* fc = f + ic*256;
        const float* wc = ws_ + ic*9;
        #pragma unroll
        for (int dy = 0; dy < 3; ++dy) {
            int y = fy + dy - 1;
            if (y < 0 || y > 15) continue;
            #pragma unroll
            for (int dx = 0; dx < 3; ++dx) {
                int xx = fx + dx - 1;
                if (xx < 0 || xx > 15) continue;
                acc += fc[y*16+xx]*wc[dy*3+dx];
            }
        }
    }
    h[c*256 + threadIdx.x] = fmaxf(acc, 0.f);
}

// ============================================================
// K3: RPN heads (1x1 convs) + softmax + anchors + decode + clip
// ============================================================
__global__ __launch_bounds__(256) void heads_rpn(const float* __restrict__ hbuf,
    const float* __restrict__ w_cls, const float* __restrict__ b_cls,
    const float* __restrict__ w_box, const float* __restrict__ b_box,
    float* __restrict__ out_logits, float* __restrict__ out_deltas,
    float* __restrict__ out_anchors,
    float* __restrict__ scores, float* __restrict__ boxes)
{
    int idx = blockIdx.x*256 + threadIdx.x;
    if (idx >= N_ANCH) return;
    int fy = idx / 144, r = idx % 144, fx = r / 9, a = r % 9;
    int pix = fy*16 + fx;
    float l0 = b_cls[a*2+0], l1 = b_cls[a*2+1];
    float d0 = b_box[a*4+0], d1 = b_box[a*4+1], d2 = b_box[a*4+2], d3 = b_box[a*4+3];
    const float* wc0 = w_cls + (a*2+0)*64;
    const float* wc1 = w_cls + (a*2+1)*64;
    const float* wb0 = w_box + (a*4+0)*64;
    const float* wb1 = w_box + (a*4+1)*64;
    const float* wb2 = w_box + (a*4+2)*64;
    const float* wb3 = w_box + (a*4+3)*64;
    for (int c = 0; c < 64; ++c) {
        float hv = hbuf[c*256 + pix];
        l0 += hv*wc0[c]; l1 += hv*wc1[c];
        d0 += hv*wb0[c]; d1 += hv*wb1[c]; d2 += hv*wb2[c]; d3 += hv*wb3[c];
    }
    out_logits[idx*2+0] = l0; out_logits[idx*2+1] = l1;
    out_deltas[idx*4+0] = d0; out_deltas[idx*4+1] = d1;
    out_deltas[idx*4+2] = d2; out_deltas[idx*4+3] = d3;
    float mx = fmaxf(l0,l1);
    float e0 = expf(l0-mx), e1 = expf(l1-mx);
    scores[idx] = e1/(e0+e1);
    // anchors
    float SC = (a/3 == 0) ? 32.f : ((a/3 == 1) ? 64.f : 128.f);
    float RT = (a%3 == 0) ? 0.5f : ((a%3 == 1) ? 1.f : 2.f);
    float wsz = SC*sqrtf(RT), hsz = SC/sqrtf(RT);
    float cx = (fx+0.5f)*16.f, cy = (fy+0.5f)*16.f;
    float ax1 = cx - wsz*0.5f, ay1 = cy - hsz*0.5f;
    float ax2 = cx + wsz*0.5f, ay2 = cy + hsz*0.5f;
    out_anchors[idx*4+0]=ax1; out_anchors[idx*4+1]=ay1;
    out_anchors[idx*4+2]=ax2; out_anchors[idx*4+3]=ay2;
    // decode + clip
    float aw = ax2-ax1, ah = ay2-ay1;
    float acx = ax1 + 0.5f*aw, acy = ay1 + 0.5f*ah;
    float ncx = acx + d0*aw, ncy = acy + d1*ah;
    float nw = aw*expf(d2), nh = ah*expf(d3);
    float x1 = ncx - 0.5f*nw, y1 = ncy - 0.5f*nh;
    float x2 = ncx + 0.5f*nw, y2 = ncy + 0.5f*nh;
    const float lim = 255.f;
    x1 = fminf(fmaxf(x1,0.f),lim); y1 = fminf(fmaxf(y1,0.f),lim);
    x2 = fminf(fmaxf(x2,0.f),lim); y2 = fminf(fmaxf(y2,0.f),lim);
    boxes[idx*4+0]=x1; boxes[idx*4+1]=y1; boxes[idx*4+2]=x2; boxes[idx*4+3]=y2;
}

// ============================================================
// stable descending argsort by rank counting (matches jnp.argsort(-s))
// ============================================================
__global__ __launch_bounds__(256) void sort_rank(const float* __restrict__ score,
                                                 int* __restrict__ order, int n)
{
    __shared__ float sc[2304];
    for (int i = threadIdx.x; i < n; i += 256) sc[i] = score[i];
    __syncthreads();
    int i = blockIdx.x*256 + threadIdx.x;
    if (i >= n) return;
    float si = sc[i];
    int r = 0;
    for (int j = 0; j < n; ++j) {
        float sj = sc[j];
        r += (sj > si) || (sj == si && j < i);
    }
    order[r] = i;
}

__global__ __launch_bounds__(256) void gather_sorted(const float4* __restrict__ boxes,
    const int* __restrict__ order, float4* __restrict__ sb, float* __restrict__ sa, int n)
{
    int i = blockIdx.x*256 + threadIdx.x;
    if (i >= n) return;
    float4 b = boxes[order[i]];
    sb[i] = b;
    sa[i] = fmaxf(b.z-b.x, 0.f)*fmaxf(b.w-b.y, 0.f);
}

// ============================================================
// IoU suppression bitmask (bits only for j > i)
// ============================================================
__global__ __launch_bounds__(256) void iou_mask(const float4* __restrict__ sb,
    const float* __restrict__ sa, int n, int words, float thr, u64* __restrict__ mask)
{
    int gid = blockIdx.x*256 + threadIdx.x;
    if (gid >= n*words) return;
    int i = gid / words, w = gid % words;
    float4 bi = sb[i]; float ai = sa[i];
    u64 m = 0;
    int j0 = w*64;
    for (int bb = 0; bb < 64; ++bb) {
        int j = j0 + bb;
        if (j > i && j < n) {
            float4 bj = sb[j];
            float xx1 = fmaxf(bi.x, bj.x), yy1 = fmaxf(bi.y, bj.y);
            float xx2 = fminf(bi.z, bj.z), yy2 = fminf(bi.w, bj.w);
            float inter = fmaxf(xx2-xx1, 0.f)*fmaxf(yy2-yy1, 0.f);
            float iou = inter / (ai + sa[j] - inter + 1e-8f);
            if (iou > thr) m |= 1ULL << bb;
        }
    }
    mask[(size_t)i*words + w] = m;
}

// single-wave sequential greedy scan
__global__ void nms_scan(const u64* __restrict__ mask, int n, int words, u64* __restrict__ remout)
{
    int lane = threadIdx.x;
    u64 rem = ~0ULL;
    for (int i = 0; i < n; ++i) {
        int w = i >> 6, b = i & 63;
        u64 rw = __shfl(rem, w);
        if ((rw >> b) & 1ULL) {
            if (lane < words) rem &= ~mask[(size_t)i*words + lane];
        }
    }
    if (lane < words) remout[lane] = rem;
}

// ============================================================
// K5c: kept-first stable selection -> proposals / valid
// ============================================================
__global__ __launch_bounds__(256) void select_props(const u64* __restrict__ remw,
    const float4* __restrict__ sboxes, float* __restrict__ prop_out,
    float4* __restrict__ propws, int* __restrict__ validat)
{
    __shared__ int cnt[256];
    __shared__ int pref[257];
    int t = threadIdx.x;
    int base = t*9;
    int c = 0;
    #pragma unroll
    for (int q = 0; q < 9; ++q) { int i = base+q; c += (int)((remw[i>>6]>>(i&63))&1ULL); }
    cnt[t] = c; __syncthreads();
    if (t == 0) { pref[0]=0; for (int u=0;u<256;u++) pref[u+1]=pref[u]+cnt[u]; }
    __syncthreads();
    int K = pref[256];
    int kb = pref[t];
    int nb = K + (base - pref[t]);
    for (int q = 0; q < 9; ++q) {
        int i = base + q;
        int k = (int)((remw[i>>6]>>(i&63))&1ULL);
        int pos = k ? kb : nb;
        if (k) kb++; else nb++;
        if (pos < NP) {
            validat[pos] = k;
            float4 p = k ? sboxes[i] : make_float4(0.f,0.f,0.f,0.f);
            propws[pos] = p;
            prop_out[pos*4+0]=p.x; prop_out[pos*4+1]=p.y;
            prop_out[pos*4+2]=p.z; prop_out[pos*4+3]=p.w;
        }
    }
}

// ============================================================
// weight transpose for mask conv: wt[(ic*9+tap)*64+oc] = w[oc*576+ic*9+tap]
// ============================================================
__global__ __launch_bounds__(256) void transpose_wm1(const float* __restrict__ w, float* __restrict__ wt)
{
    int e = blockIdx.x*256 + threadIdx.x;
    if (e >= 36864) return;
    int oc = e / 576, rem = e % 576;
    wt[rem*64 + oc] = w[e];
}

// ============================================================
// K6: crop_resize + 2x2 maxpool -> flat [2000, 3136]
// ============================================================
__global__ __launch_bounds__(256) void pool_flat(const float* __restrict__ feat,
    const float4* __restrict__ propws, float* __restrict__ flat)
{
    __shared__ float f[16384];
    for (int e = threadIdx.x; e < 16384; e += 256) f[e] = feat[e];
    __syncthreads();
    int n = blockIdx.x;
    float4 p = propws[n];
    float x1n = p.x*(1.f/255.f), y1n = p.y*(1.f/255.f);
    float x2n = p.z*(1.f/255.f), y2n = p.w*(1.f/255.f);
    for (int o = threadIdx.x; o < 3136; o += 256) {
        int c = o/49, r2 = o%49, py = r2/7, px = r2%7;
        float mx = -1e30f;
        #pragma unroll
        for (int sy = 0; sy < 2; ++sy) {
            int iy = py*2+sy;
            float ty = iy*(1.f/13.f);
            float fyv = (y1n + (y2n-y1n)*ty)*15.f;
            int y0 = min(max((int)floorf(fyv),0),15);
            int y1i = min(y0+1,15);
            float wy = fyv - (float)y0;
            #pragma unroll
            for (int sx = 0; sx < 2; ++sx) {
                int ix = px*2+sx;
                float tx = ix*(1.f/13.f);
                float fxv = (x1n + (x2n-x1n)*tx)*15.f;
                int x0 = min(max((int)floorf(fxv),0),15);
                int x1i = min(x0+1,15);
                float wx = fxv - (float)x0;
                const float* fc = f + c*256;
                float top = fc[y0*16+x0]*(1.f-wx) + fc[y0*16+x1i]*wx;
                float bot = fc[y1i*16+x0]*(1.f-wx) + fc[y1i*16+x1i]*wx;
                float val = top*(1.f-wy) + bot*wy;
                mx = fmaxf(mx, val);
            }
        }
        flat[(size_t)n*3136 + o] = mx;
    }
}

// ============================================================
// tiled f32 GEMM: C[M,N] = act(A[M,K] @ B[K,N] + bias)
// ============================================================
__global__ __launch_bounds__(256) void gemm_bias_act(const float* __restrict__ A,
    const float* __restrict__ B, const float* __restrict__ bias, float* __restrict__ C,
    int M, int N, int K, int do_relu)
{
    __shared__ float As[16][65];
    __shared__ float Bs[16][65];
    int tx = threadIdx.x & 15, ty = threadIdx.x >> 4;
    int row0 = blockIdx.x*64, col0 = blockIdx.y*64;
    float acc[4][4] = {};
    for (int k0 = 0; k0 < K; k0 += 16) {
        {
            int r = threadIdx.x >> 2;
            int kq = (threadIdx.x & 3)*4;
            int gm = row0 + r;
            float4 v = make_float4(0.f,0.f,0.f,0.f);
            if (gm < M) v = *(const float4*)(A + (size_t)gm*K + k0 + kq);
            As[kq+0][r]=v.x; As[kq+1][r]=v.y; As[kq+2][r]=v.z; As[kq+3][r]=v.w;
        }
        {
            int kk = threadIdx.x >> 4;
            int nq = (threadIdx.x & 15)*4;
            float4 v = *(const float4*)(B + (size_t)(k0+kk)*N + col0 + nq);
            Bs[kk][nq+0]=v.x; Bs[kk][nq+1]=v.y; Bs[kk][nq+2]=v.z; Bs[kk][nq+3]=v.w;
        }
        __syncthreads();
        #pragma unroll
        for (int k = 0; k < 16; ++k) {
            float a[4], b[4];
            #pragma unroll
            for (int i = 0; i < 4; ++i) a[i] = As[k][ty*4+i];
            #pragma unroll
            for (int j = 0; j < 4; ++j) b[j] = Bs[k][tx*4+j];
            #pragma unroll
            for (int i = 0; i < 4; ++i)
                #pragma unroll
                for (int j = 0; j < 4; ++j) acc[i][j] = fmaf(a[i], b[j], acc[i][j]);
        }
        __syncthreads();
    }
    #pragma unroll
    for (int i = 0; i < 4; ++i) {
        int gm = row0 + ty*4 + i;
        if (gm >= M) continue;
        #pragma unroll
        for (int j = 0; j < 4; ++j) {
            int gn = col0 + tx*4 + j;
            float v = acc[i][j] + bias[gn];
            if (do_relu) v = fmaxf(v, 0.f);
            C[(size_t)gm*N + gn] = v;
        }
    }
}

// ============================================================
// K9: rcnn heads + softmax + decode + clip + s2
// ============================================================
__global__ __launch_bounds__(256) void rcnn_heads(const float* __restrict__ h2,
    const float* __restrict__ w_rcls, const float* __restrict__ b_rcls,
    const float* __restrict__ w_rbox, const float* __restrict__ b_rbox,
    const float4* __restrict__ propws, const int* __restrict__ validat,
    float* __restrict__ out_logits, float* __restrict__ out_deltas,
    float4* __restrict__ dets, float* __restrict__ dscores, float* __restrict__ s2)
{
    int n = blockIdx.x*256 + threadIdx.x;
    if (n >= NP) return;
    const float* hv = h2 + (size_t)n*512;
    float l0 = b_rcls[0], l1 = b_rcls[1];
    float d0 = b_rbox[0], d1 = b_rbox[1], d2 = b_rbox[2], d3 = b_rbox[3];
    for (int k = 0; k < 512; ++k) {
        float v = hv[k];
        l0 += v*w_rcls[k*2+0]; l1 += v*w_rcls[k*2+1];
        d0 += v*w_rbox[k*4+0]; d1 += v*w_rbox[k*4+1];
        d2 += v*w_rbox[k*4+2]; d3 += v*w_rbox[k*4+3];
    }
    out_logits[n*2+0]=l0; out_logits[n*2+1]=l1;
    out_deltas[n*4+0]=d0; out_deltas[n*4+1]=d1;
    out_deltas[n*4+2]=d2; out_deltas[n*4+3]=d3;
    float mx = fmaxf(l0,l1);
    float e0 = expf(l0-mx), e1 = expf(l1-mx);
    float sc = e1/(e0+e1);
    float4 p = propws[n];
    float w = p.z-p.x, h = p.w-p.y;
    float cx = p.x + 0.5f*w, cy = p.y + 0.5f*h;
    float ncx = cx + d0*w, ncy = cy + d1*h;
    float nw = w*expf(d2), nh = h*expf(d3);
    float x1 = ncx-0.5f*nw, y1 = ncy-0.5f*nh, x2 = ncx+0.5f*nw, y2 = ncy+0.5f*nh;
    const float lim = 255.f;
    x1 = fminf(fmaxf(x1,0.f),lim); y1 = fminf(fmaxf(y1,0.f),lim);
    x2 = fminf(fmaxf(x2,0.f),lim); y2 = fminf(fmaxf(y2,0.f),lim);
    dets[n] = make_float4(x1,y1,x2,y2);
    dscores[n] = sc;
    s2[n] = validat[n] ? sc : -1.0f;
}

// ============================================================
// K10: fused crop_resize + mask conv1 (3x3,64->64,relu) + conv2 (1x1,64->1)
// ============================================================
__global__ __launch_bounds__(256) void mask_head(const float* __restrict__ feat,
    const float4* __restrict__ propws, const float* __restrict__ wt,
    const float* __restrict__ b_m1, const float* __restrict__ w_m2,
    const float* __restrict__ b_m2, float* __restrict__ masks_out)
{
    __shared__ float crop[64*196];
    int n = blockIdx.x;
    float4 p = propws[n];
    float x1n = p.x*(1.f/255.f), y1n = p.y*(1.f/255.f);
    float x2n = p.z*(1.f/255.f), y2n = p.w*(1.f/255.f);
    for (int e = threadIdx.x; e < 64*196; e += 256) {
        int c = e/196, pp = e%196, yy = pp/14, xx = pp%14;
        float ty = yy*(1.f/13.f), tx = xx*(1.f/13.f);
        float fyv = (y1n + (y2n-y1n)*ty)*15.f;
        float fxv = (x1n + (x2n-x1n)*tx)*15.f;
        int y0 = min(max((int)floorf(fyv),0),15); int y1i = min(y0+1,15);
        int x0 = min(max((int)floorf(fxv),0),15); int x1i = min(x0+1,15);
        float wy = fyv - (float)y0, wx = fxv - (float)x0;
        const float* fc = feat + c*256;
        float top = fc[y0*16+x0]*(1.f-wx) + fc[y0*16+x1i]*wx;
        float bot = fc[y1i*16+x0]*(1.f-wx) + fc[y1i*16+x1i]*wx;
        crop[e] = top*(1.f-wy) + bot*wy;
    }
    __syncthreads();
    int t = threadIdx.x;
    if (t >= 196) return;
    int py = t/14, px = t%14;
    float acc[64];
    #pragma unroll
    for (int oc = 0; oc < 64; ++oc) acc[oc] = b_m1[oc];
    #pragma unroll 1
    for (int ic = 0; ic < 64; ++ic) {
        const float* cb = crop + ic*196;
        #pragma unroll
        for (int dy = 0; dy < 3; ++dy) {
            int y = py + dy - 1;
            bool oky = (y >= 0) && (y < 14);
            int yc = min(max(y,0),13);
            #pragma unroll
            for (int dx = 0; dx < 3; ++dx) {
                int x = px + dx - 1;
                bool ok = oky && (x >= 0) && (x < 14);
                int xc = min(max(x,0),13);
                float v = cb[yc*14 + xc];
                v = ok ? v : 0.f;
                const float* wp = wt + (ic*9 + dy*3 + dx)*64;
                #pragma unroll
                for (int oc = 0; oc < 64; ++oc) acc[oc] = fmaf(v, wp[oc], acc[oc]);
            }
        }
    }
    float msk = b_m2[0];
    #pragma unroll
    for (int oc = 0; oc < 64; ++oc) msk += fmaxf(acc[oc], 0.f)*w_m2[oc];
    masks_out[(size_t)n*196 + t] = msk;
}

// ============================================================
// K12e: final outputs
// ============================================================
__global__ __launch_bounds__(256) void finalize(const u64* __restrict__ remw2,
    const int* __restrict__ order2, const int* __restrict__ validat,
    const float4* __restrict__ dets, const float* __restrict__ dscores,
    const float* __restrict__ masks_in, float* __restrict__ fdets,
    float* __restrict__ fscores, float* __restrict__ fmasks, float* __restrict__ keep2out)
{
    int j = blockIdx.x;
    int t = threadIdx.x;
    int o = order2[j];
    int kb = (int)((remw2[j>>6] >> (j&63)) & 1ULL);
    int k2 = kb & validat[o];
    if (t == 0) {
        float4 d = dets[o];
        if (!k2) d = make_float4(0.f,0.f,0.f,0.f);
        fdets[j*4+0]=d.x; fdets[j*4+1]=d.y; fdets[j*4+2]=d.z; fdets[j*4+3]=d.w;
        fscores[j] = k2 ? dscores[o] : 0.f;
        keep2out[j] = (float)k2;
    }
    if (t < 196) {
        float mv = masks_in[(size_t)o*196 + t];
        float sg = 1.f/(1.f + expf(-mv));
        fmasks[(size_t)j*196 + t] = k2 ? sg : 0.f;
    }
}

// ============================================================
extern "C" void kernel_launch(void* const* d_in, const int* in_sizes, int n_in,
                              void* d_out, int out_size, void* d_ws, size_t ws_size,
                              hipStream_t stream)
{
    const float* x      = (const float*)d_in[0];
    const float* w_bb   = (const float*)d_in[1];
    const float* b_bb   = (const float*)d_in[2];
    const float* w_rpn  = (const float*)d_in[3];
    const float* b_rpn  = (const float*)d_in[4];
    const float* w_cls  = (const float*)d_in[5];
    const float* b_cls  = (const float*)d_in[6];
    const float* w_box  = (const float*)d_in[7];
    const float* b_box  = (const float*)d_in[8];
    const float* w_fc1  = (const float*)d_in[9];
    const float* b_fc1  = (const float*)d_in[10];
    const float* w_fc2  = (const float*)d_in[11];
    const float* b_fc2  = (const float*)d_in[12];
    const float* w_rcls = (const float*)d_in[13];
    const float* b_rcls = (const float*)d_in[14];
    const float* w_rbox = (const float*)d_in[15];
    const float* b_rbox = (const float*)d_in[16];
    const float* w_m1   = (const float*)d_in[17];
    const float* b_m1   = (const float*)d_in[18];
    const float* w_m2   = (const float*)d_in[19];
    const float* b_m2   = (const float*)d_in[20];

    float* out = (float*)d_out;

    // ---- workspace carve-up ----
    float* feat    = (float*)d_ws;              // 16384
    float* hbuf    = feat + 16384;              // 16384
    float* scores  = hbuf + 16384;              // 2304
    float* boxes   = scores + 2304;             // 9216
    int*   order1  = (int*)(boxes + 9216);      // 2304
    float* sboxes  = (float*)(order1 + 2304);   // 9216  (16B aligned)
    float* sareas  = sboxes + 9216;             // 2304
    u64*   supm1   = (u64*)(sareas + 2304);     // 82944 (8B aligned)
    u64*   remw1   = supm1 + 82944;             // 36
    int*   validat = (int*)(remw1 + 36);        // 2000
    float* propws  = (float*)(validat + 2000);  // 8000  (16B aligned)
    float* wt      = propws + 8000;             // 36864
    float* flat    = wt + 36864;                // 6272000
    float* h1      = flat + 6272000;            // 1024000
    float* h2      = h1 + 1024000;              // 1024000
    float* dets    = h2 + 1024000;              // 8000  (16B aligned)
    float* dscores = dets + 8000;               // 2000
    float* s2      = dscores + 2000;            // 2000
    int*   order2  = (int*)(s2 + 2000);         // 2000
    float* sdets   = (float*)(order2 + 2000);   // 8000  (16B aligned)
    float* sareas2 = sdets + 8000;              // 2000
    u64*   supm2   = (u64*)(sareas2 + 2000);    // 64000 (8B aligned)
    u64*   remw2   = supm2 + 64000;             // 32

    // ---- stage 1: backbone + rpn ----
    bb_conv<<<64, 256, 0, stream>>>(x, w_bb, b_bb, feat);
    rpn_conv<<<64, 256, 0, stream>>>(feat, w_rpn, b_rpn, hbuf);
    heads_rpn<<<9, 256, 0, stream>>>(hbuf, w_cls, b_cls, w_box, b_box,
        out + O_RPN_LOGITS, out + O_RPN_DELTAS, out + O_ANCHORS, scores, boxes);

    // ---- NMS 1 ----
    sort_rank<<<9, 256, 0, stream>>>(scores, order1, N_ANCH);
    gather_sorted<<<9, 256, 0, stream>>>((const float4*)boxes, order1,
                                         (float4*)sboxes, sareas, N_ANCH);
    iou_mask<<<(N_ANCH*W1)/256, 256, 0, stream>>>((const float4*)sboxes, sareas,
                                                  N_ANCH, W1, 0.5f, supm1);
    nms_scan<<<1, 64, 0, stream>>>(supm1, N_ANCH, W1, remw1);
    select_props<<<1, 256, 0, stream>>>(remw1, (const float4*)sboxes,
                                        out + O_PROPOSALS, (float4*)propws, validat);

    // ---- RoI head ----
    transpose_wm1<<<144, 256, 0, stream>>>(w_m1, wt);
    pool_flat<<<NP, 256, 0, stream>>>(feat, (const float4*)propws, flat);
    gemm_bias_act<<<dim3(32, 8), 256, 0, stream>>>(flat, w_fc1, b_fc1, h1, NP, 512, 3136, 1);
    gemm_bias_act<<<dim3(32, 8), 256, 0, stream>>>(h1, w_fc2, b_fc2, h2, NP, 512, 512, 1);
    rcnn_heads<<<8, 256, 0, stream>>>(h2, w_rcls, b_rcls, w_rbox, b_rbox,
        (const float4*)propws, validat, out + O_RCNN_LOGITS, out + O_RCNN_DELTAS,
        (float4*)dets, dscores, s2);
    mask_head<<<NP, 256, 0, stream>>>(feat, (const float4*)propws, wt, b_m1, w_m2, b_m2,
                                      out + O_RCNN_MASKS);

    // ---- NMS 2 + finalize ----
    sort_rank<<<8, 256, 0, stream>>>(s2, order2, NP);
    gather_sorted<<<8, 256, 0, stream>>>((const float4*)dets, order2,
                                         (float4*)sdets, sareas2, NP);
    iou_mask<<<(NP*W2)/256, 256, 0, stream>>>((const float4*)sdets, sareas2,
                                              NP, W2, 0.3f, supm2);
    nms_scan<<<1, 64, 0, stream>>>(supm2, NP, W2, remw2);
    finalize<<<NP, 256, 0, stream>>>(remw2, order2, validat, (const float4*)dets,
        dscores, out + O_RCNN_MASKS, out + O_FINAL_DETS, out + O_FINAL_SCORES,
        out + O_FINAL_MASKS, out + O_KEEP2);
}

// Round 2
// 1287.418 us; speedup vs baseline: 1.5502x; 1.5502x over previous
//
#include <hip/hip_runtime.h>
#include <math.h>

typedef unsigned long long u64;
typedef unsigned short u16;
typedef __attribute__((ext_vector_type(8))) short bf16x8;
typedef __attribute__((ext_vector_type(4))) float f32x4;

#define N_ANCH 2304
#define NP     2000
#define W1     36   // 2304/64
#define W2     32   // ceil(2000/64)

// ---------- output offsets (floats) ----------
#define O_RPN_LOGITS   0
#define O_RPN_DELTAS   4608
#define O_PROPOSALS    13824
#define O_ANCHORS      21824
#define O_RCNN_LOGITS  31040
#define O_RCNN_DELTAS  35040
#define O_RCNN_MASKS   43040
#define O_FINAL_DETS   435040
#define O_FINAL_MASKS  443040
#define O_FINAL_SCORES 835040
#define O_KEEP2        837040

__device__ __forceinline__ u16 f2bf(float f) {
    unsigned int x = __float_as_uint(f);
    unsigned int r = x + 0x7fffu + ((x >> 16) & 1u);   // RTNE
    return (u16)(r >> 16);
}

// ============================================================
// K1: backbone 16x16 stride-16 VALID conv + relu -> feat [64,16,16]
// ============================================================
__global__ __launch_bounds__(256) void bb_conv(const float* __restrict__ x,
    const float* __restrict__ w, const float* __restrict__ b, float* __restrict__ feat)
{
    __shared__ float ws_[768];
    int c = blockIdx.x;
    for (int e = threadIdx.x; e < 768; e += 256) ws_[e] = w[c*768 + e];
    __syncthreads();
    int fy = threadIdx.x >> 4, fx = threadIdx.x & 15;
    float acc = b[c];
    for (int ic = 0; ic < 3; ++ic)
        for (int ky = 0; ky < 16; ++ky) {
            const float* xr = x + (size_t)(ic*256 + fy*16+ky)*256 + fx*16;
            const float* wr = ws_ + ic*256 + ky*16;
            #pragma unroll
            for (int kx = 0; kx < 16; ++kx) acc += xr[kx]*wr[kx];
        }
    feat[c*256 + threadIdx.x] = fmaxf(acc, 0.f);
}

// ============================================================
// K2: RPN 3x3 SAME conv + relu -> h [64,16,16]
// ============================================================
__global__ __launch_bounds__(256) void rpn_conv(const float* __restrict__ feat,
    const float* __restrict__ w, const float* __restrict__ b, float* __restrict__ h)
{
    __shared__ float f[16384];
    __shared__ float ws_[576];
    int c = blockIdx.x;
    for (int e = threadIdx.x; e < 16384; e += 256) f[e] = feat[e];
    for (int e = threadIdx.x; e < 576; e += 256) ws_[e] = w[c*576 + e];
    __syncthreads();
    int fy = threadIdx.x >> 4, fx = threadIdx.x & 15;
    float acc = b[c];
    for (int ic = 0; ic < 64; ++ic) {
        const float* fc = f + ic*256;
        const float* wc = ws_ + ic*9;
        #pragma unroll
        for (int dy = 0; dy < 3; ++dy) {
            int y = fy + dy - 1;
            if (y < 0 || y > 15) continue;
            #pragma unroll
            for (int dx = 0; dx < 3; ++dx) {
                int xx = fx + dx - 1;
                if (xx < 0 || xx > 15) continue;
                acc += fc[y*16+xx]*wc[dy*3+dx];
            }
        }
    }
    h[c*256 + threadIdx.x] = fmaxf(acc, 0.f);
}

// ============================================================
// K3: RPN heads (1x1 convs) + softmax + anchors + decode + clip
// ============================================================
__global__ __launch_bounds__(256) void heads_rpn(const float* __restrict__ hbuf,
    const float* __restrict__ w_cls, const float* __restrict__ b_cls,
    const float* __restrict__ w_box, const float* __restrict__ b_box,
    float* __restrict__ out_logits, float* __restrict__ out_deltas,
    float* __restrict__ out_anchors,
    float* __restrict__ scores, float* __restrict__ boxes)
{
    int idx = blockIdx.x*256 + threadIdx.x;
    if (idx >= N_ANCH) return;
    int fy = idx / 144, r = idx % 144, fx = r / 9, a = r % 9;
    int pix = fy*16 + fx;
    float l0 = b_cls[a*2+0], l1 = b_cls[a*2+1];
    float d0 = b_box[a*4+0], d1 = b_box[a*4+1], d2 = b_box[a*4+2], d3 = b_box[a*4+3];
    const float* wc0 = w_cls + (a*2+0)*64;
    const float* wc1 = w_cls + (a*2+1)*64;
    const float* wb0 = w_box + (a*4+0)*64;
    const float* wb1 = w_box + (a*4+1)*64;
    const float* wb2 = w_box + (a*4+2)*64;
    const float* wb3 = w_box + (a*4+3)*64;
    for (int c = 0; c < 64; ++c) {
        float hv = hbuf[c*256 + pix];
        l0 += hv*wc0[c]; l1 += hv*wc1[c];
        d0 += hv*wb0[c]; d1 += hv*wb1[c]; d2 += hv*wb2[c]; d3 += hv*wb3[c];
    }
    out_logits[idx*2+0] = l0; out_logits[idx*2+1] = l1;
    out_deltas[idx*4+0] = d0; out_deltas[idx*4+1] = d1;
    out_deltas[idx*4+2] = d2; out_deltas[idx*4+3] = d3;
    float mx = fmaxf(l0,l1);
    float e0 = expf(l0-mx), e1 = expf(l1-mx);
    scores[idx] = e1/(e0+e1);
    float SC = (a/3 == 0) ? 32.f : ((a/3 == 1) ? 64.f : 128.f);
    float RT = (a%3 == 0) ? 0.5f : ((a%3 == 1) ? 1.f : 2.f);
    float wsz = SC*sqrtf(RT), hsz = SC/sqrtf(RT);
    float cx = (fx+0.5f)*16.f, cy = (fy+0.5f)*16.f;
    float ax1 = cx - wsz*0.5f, ay1 = cy - hsz*0.5f;
    float ax2 = cx + wsz*0.5f, ay2 = cy + hsz*0.5f;
    out_anchors[idx*4+0]=ax1; out_anchors[idx*4+1]=ay1;
    out_anchors[idx*4+2]=ax2; out_anchors[idx*4+3]=ay2;
    float aw = ax2-ax1, ah = ay2-ay1;
    float acx = ax1 + 0.5f*aw, acy = ay1 + 0.5f*ah;
    float ncx = acx + d0*aw, ncy = acy + d1*ah;
    float nw = aw*expf(d2), nh = ah*expf(d3);
    float x1 = ncx - 0.5f*nw, y1 = ncy - 0.5f*nh;
    float x2 = ncx + 0.5f*nw, y2 = ncy + 0.5f*nh;
    const float lim = 255.f;
    x1 = fminf(fmaxf(x1,0.f),lim); y1 = fminf(fmaxf(y1,0.f),lim);
    x2 = fminf(fmaxf(x2,0.f),lim); y2 = fminf(fmaxf(y2,0.f),lim);
    boxes[idx*4+0]=x1; boxes[idx*4+1]=y1; boxes[idx*4+2]=x2; boxes[idx*4+3]=y2;
}

// ============================================================
// stable descending argsort by rank counting (matches jnp.argsort(-s))
// ============================================================
__global__ __launch_bounds__(256) void sort_rank(const float* __restrict__ score,
                                                 int* __restrict__ order, int n)
{
    __shared__ float sc[2304];
    for (int i = threadIdx.x; i < n; i += 256) sc[i] = score[i];
    __syncthreads();
    int i = blockIdx.x*256 + threadIdx.x;
    if (i >= n) return;
    float si = sc[i];
    int r = 0;
    for (int j = 0; j < n; ++j) {
        float sj = sc[j];
        r += (sj > si) || (sj == si && j < i);
    }
    order[r] = i;
}

__global__ __launch_bounds__(256) void gather_sorted(const float4* __restrict__ boxes,
    const int* __restrict__ order, float4* __restrict__ sb, float* __restrict__ sa, int n)
{
    int i = blockIdx.x*256 + threadIdx.x;
    if (i >= n) return;
    float4 b = boxes[order[i]];
    sb[i] = b;
    sa[i] = fmaxf(b.z-b.x, 0.f)*fmaxf(b.w-b.y, 0.f);
}

// ============================================================
// IoU suppression bitmask (bits only for j > i)
// ============================================================
__global__ __launch_bounds__(256) void iou_mask(const float4* __restrict__ sb,
    const float* __restrict__ sa, int n, int words, float thr, u64* __restrict__ mask)
{
    int gid = blockIdx.x*256 + threadIdx.x;
    if (gid >= n*words) return;
    int i = gid / words, w = gid % words;
    float4 bi = sb[i]; float ai = sa[i];
    u64 m = 0;
    int j0 = w*64;
    for (int bb = 0; bb < 64; ++bb) {
        int j = j0 + bb;
        if (j > i && j < n) {
            float4 bj = sb[j];
            float xx1 = fmaxf(bi.x, bj.x), yy1 = fmaxf(bi.y, bj.y);
            float xx2 = fminf(bi.z, bj.z), yy2 = fminf(bi.w, bj.w);
            float inter = fmaxf(xx2-xx1, 0.f)*fmaxf(yy2-yy1, 0.f);
            float iou = inter / (ai + sa[j] - inter + 1e-8f);
            if (iou > thr) m |= 1ULL << bb;
        }
    }
    mask[(size_t)i*words + w] = m;
}

// ============================================================
// single-wave greedy scan, software-pipelined (prefetch depth 16).
// Serial chain is only: cur -> alive -> cur&~sw (pure VALU).
// rem word for current 64-block is replicated in `cur`; the diagonal
// word `sw` comes from the prefetched row (off the serial chain).
// n must be a multiple of 16; mask must have >=16 rows of slack.
// ============================================================
__global__ void nms_scan(const u64* __restrict__ mask, int n, int words, u64* __restrict__ remout)
{
    int lane = threadIdx.x;
    bool act = lane < words;
    const u64* mrow = mask + lane;
    u64 pre[16];
    #pragma unroll
    for (int d = 0; d < 16; ++d)
        pre[d] = act ? mrow[(size_t)d*words] : 0;
    u64 rem = ~0ULL;
    u64 cur = 0;
    for (int i0 = 0; i0 < n; i0 += 16) {
        int w = i0 >> 6;
        if ((i0 & 63) == 0) cur = __shfl(rem, w);
        #pragma unroll
        for (int d = 0; d < 16; ++d) {
            int i = i0 + d;
            u64 row = pre[d];
            pre[d] = act ? mrow[(size_t)(i+16)*words] : 0;  // prefetch (slack rows)
            u64 sw = __shfl(row, w);
            bool alive = (cur >> (i & 63)) & 1ULL;
            rem &= alive ? ~row : ~0ULL;
            cur &= alive ? ~sw : ~0ULL;
        }
    }
    if (act) remout[lane] = rem;
}

// ============================================================
// kept-first stable selection -> proposals / valid
// ============================================================
__global__ __launch_bounds__(256) void select_props(const u64* __restrict__ remw,
    const float4* __restrict__ sboxes, float* __restrict__ prop_out,
    float4* __restrict__ propws, int* __restrict__ validat)
{
    __shared__ int cnt[256];
    __shared__ int pref[257];
    int t = threadIdx.x;
    int base = t*9;
    int c = 0;
    #pragma unroll
    for (int q = 0; q < 9; ++q) { int i = base+q; c += (int)((remw[i>>6]>>(i&63))&1ULL); }
    cnt[t] = c; __syncthreads();
    if (t == 0) { pref[0]=0; for (int u=0;u<256;u++) pref[u+1]=pref[u]+cnt[u]; }
    __syncthreads();
    int K = pref[256];
    int kb = pref[t];
    int nb = K + (base - pref[t]);
    for (int q = 0; q < 9; ++q) {
        int i = base + q;
        int k = (int)((remw[i>>6]>>(i&63))&1ULL);
        int pos = k ? kb : nb;
        if (k) kb++; else nb++;
        if (pos < NP) {
            validat[pos] = k;
            float4 p = k ? sboxes[i] : make_float4(0.f,0.f,0.f,0.f);
            propws[pos] = p;
            prop_out[pos*4+0]=p.x; prop_out[pos*4+1]=p.y;
            prop_out[pos*4+2]=p.z; prop_out[pos*4+3]=p.w;
        }
    }
}

// ============================================================
// weight prep for MFMA mask conv: wbt[tap][oc][ic] (bf16)
// ============================================================
__global__ __launch_bounds__(256) void prep_wbt(const float* __restrict__ w, u16* __restrict__ wbt)
{
    int e = blockIdx.x*256 + threadIdx.x;
    if (e >= 36864) return;
    int oc = e / 576, rem = e % 576, ic = rem / 9, tap = rem % 9;
    wbt[tap*4096 + oc*64 + ic] = f2bf(w[e]);
}

// ============================================================
// K6: crop_resize + 2x2 maxpool -> flat [2000, 3136]
// ============================================================
__global__ __launch_bounds__(256) void pool_flat(const float* __restrict__ feat,
    const float4* __restrict__ propws, float* __restrict__ flat)
{
    __shared__ float f[16384];
    for (int e = threadIdx.x; e < 16384; e += 256) f[e] = feat[e];
    __syncthreads();
    int n = blockIdx.x;
    float4 p = propws[n];
    float x1n = p.x*(1.f/255.f), y1n = p.y*(1.f/255.f);
    float x2n = p.z*(1.f/255.f), y2n = p.w*(1.f/255.f);
    for (int o = threadIdx.x; o < 3136; o += 256) {
        int c = o/49, r2 = o%49, py = r2/7, px = r2%7;
        float mx = -1e30f;
        #pragma unroll
        for (int sy = 0; sy < 2; ++sy) {
            int iy = py*2+sy;
            float ty = iy*(1.f/13.f);
            float fyv = (y1n + (y2n-y1n)*ty)*15.f;
            int y0 = min(max((int)floorf(fyv),0),15);
            int y1i = min(y0+1,15);
            float wy = fyv - (float)y0;
            #pragma unroll
            for (int sx = 0; sx < 2; ++sx) {
                int ix = px*2+sx;
                float tx = ix*(1.f/13.f);
                float fxv = (x1n + (x2n-x1n)*tx)*15.f;
                int x0 = min(max((int)floorf(fxv),0),15);
                int x1i = min(x0+1,15);
                float wx = fxv - (float)x0;
                const float* fc = f + c*256;
                float top = fc[y0*16+x0]*(1.f-wx) + fc[y0*16+x1i]*wx;
                float bot = fc[y1i*16+x0]*(1.f-wx) + fc[y1i*16+x1i]*wx;
                float val = top*(1.f-wy) + bot*wy;
                mx = fmaxf(mx, val);
            }
        }
        flat[(size_t)n*3136 + o] = mx;
    }
}

// ============================================================
// tiled f32 GEMM: C[M,N] = act(A[M,K] @ B[K,N] + bias)
// ============================================================
__global__ __launch_bounds__(256) void gemm_bias_act(const float* __restrict__ A,
    const float* __restrict__ B, const float* __restrict__ bias, float* __restrict__ C,
    int M, int N, int K, int do_relu)
{
    __shared__ float As[16][65];
    __shared__ float Bs[16][65];
    int tx = threadIdx.x & 15, ty = threadIdx.x >> 4;
    int row0 = blockIdx.x*64, col0 = blockIdx.y*64;
    float acc[4][4] = {};
    for (int k0 = 0; k0 < K; k0 += 16) {
        {
            int r = threadIdx.x >> 2;
            int kq = (threadIdx.x & 3)*4;
            int gm = row0 + r;
            float4 v = make_float4(0.f,0.f,0.f,0.f);
            if (gm < M) v = *(const float4*)(A + (size_t)gm*K + k0 + kq);
            As[kq+0][r]=v.x; As[kq+1][r]=v.y; As[kq+2][r]=v.z; As[kq+3][r]=v.w;
        }
        {
            int kk = threadIdx.x >> 4;
            int nq = (threadIdx.x & 15)*4;
            float4 v = *(const float4*)(B + (size_t)(k0+kk)*N + col0 + nq);
            Bs[kk][nq+0]=v.x; Bs[kk][nq+1]=v.y; Bs[kk][nq+2]=v.z; Bs[kk][nq+3]=v.w;
        }
        __syncthreads();
        #pragma unroll
        for (int k = 0; k < 16; ++k) {
            float a[4], b[4];
            #pragma unroll
            for (int i = 0; i < 4; ++i) a[i] = As[k][ty*4+i];
            #pragma unroll
            for (int j = 0; j < 4; ++j) b[j] = Bs[k][tx*4+j];
            #pragma unroll
            for (int i = 0; i < 4; ++i)
                #pragma unroll
                for (int j = 0; j < 4; ++j) acc[i][j] = fmaf(a[i], b[j], acc[i][j]);
        }
        __syncthreads();
    }
    #pragma unroll
    for (int i = 0; i < 4; ++i) {
        int gm = row0 + ty*4 + i;
        if (gm >= M) continue;
        #pragma unroll
        for (int j = 0; j < 4; ++j) {
            int gn = col0 + tx*4 + j;
            float v = acc[i][j] + bias[gn];
            if (do_relu) v = fmaxf(v, 0.f);
            C[(size_t)gm*N + gn] = v;
        }
    }
}

// ============================================================
// K9: rcnn heads + softmax + decode + clip + s2
// ============================================================
__global__ __launch_bounds__(256) void rcnn_heads(const float* __restrict__ h2,
    const float* __restrict__ w_rcls, const float* __restrict__ b_rcls,
    const float* __restrict__ w_rbox, const float* __restrict__ b_rbox,
    const float4* __restrict__ propws, const int* __restrict__ validat,
    float* __restrict__ out_logits, float* __restrict__ out_deltas,
    float4* __restrict__ dets, float* __restrict__ dscores, float* __restrict__ s2)
{
    int n = blockIdx.x*256 + threadIdx.x;
    if (n >= NP) return;
    const float* hv = h2 + (size_t)n*512;
    float l0 = b_rcls[0], l1 = b_rcls[1];
    float d0 = b_rbox[0], d1 = b_rbox[1], d2 = b_rbox[2], d3 = b_rbox[3];
    for (int k = 0; k < 512; ++k) {
        float v = hv[k];
        l0 += v*w_rcls[k*2+0]; l1 += v*w_rcls[k*2+1];
        d0 += v*w_rbox[k*4+0]; d1 += v*w_rbox[k*4+1];
        d2 += v*w_rbox[k*4+2]; d3 += v*w_rbox[k*4+3];
    }
    out_logits[n*2+0]=l0; out_logits[n*2+1]=l1;
    out_deltas[n*4+0]=d0; out_deltas[n*4+1]=d1;
    out_deltas[n*4+2]=d2; out_deltas[n*4+3]=d3;
    float mx = fmaxf(l0,l1);
    float e0 = expf(l0-mx), e1 = expf(l1-mx);
    float sc = e1/(e0+e1);
    float4 p = propws[n];
    float w = p.z-p.x, h = p.w-p.y;
    float cx = p.x + 0.5f*w, cy = p.y + 0.5f*h;
    float ncx = cx + d0*w, ncy = cy + d1*h;
    float nw = w*expf(d2), nh = h*expf(d3);
    float x1 = ncx-0.5f*nw, y1 = ncy-0.5f*nh, x2 = ncx+0.5f*nw, y2 = ncy+0.5f*nh;
    const float lim = 255.f;
    x1 = fminf(fmaxf(x1,0.f),lim); y1 = fminf(fmaxf(y1,0.f),lim);
    x2 = fminf(fmaxf(x2,0.f),lim); y2 = fminf(fmaxf(y2,0.f),lim);
    dets[n] = make_float4(x1,y1,x2,y2);
    dscores[n] = sc;
    s2[n] = validat[n] ? sc : -1.0f;
}

// ============================================================
// K10: MFMA mask head. Per-proposal implicit GEMM:
//   D[pixel(196->208 pad), oc(64)] = crop[pixel, ic] @ W[tap][ic, oc], summed over 9 taps
// crop staged in LDS as bf16 on a 16x16 haloed grid (rows 0..255) + zero
// rows 256..291; tap shift = single row-offset, no bounds math in K-loop.
// Row stride 72 shorts (144B): ds_read_b128 lanes collide only 2-way (free).
// Wave w owns oc tile w (16 oc); 13 pixel tiles of 16 -> 13 C-frags/wave.
// ============================================================
__global__ __launch_bounds__(256) void mask_head_mfma(const float* __restrict__ feat,
    const float4* __restrict__ propws, const u16* __restrict__ wbt,
    const float* __restrict__ b_m1, const float* __restrict__ w_m2,
    const float* __restrict__ b_m2, float* __restrict__ masks_out)
{
    __shared__ __align__(16) u16 crop[292*72];
    __shared__ float part[4*208];
    int n = blockIdx.x;
    float4 p = propws[n];
    float x1n = p.x*(1.f/255.f), y1n = p.y*(1.f/255.f);
    float x2n = p.z*(1.f/255.f), y2n = p.w*(1.f/255.f);
    // zero everything, then fill real pixels
    for (int e = threadIdx.x; e < 292*72; e += 256) crop[e] = 0;
    __syncthreads();
    for (int e = threadIdx.x; e < 256*64; e += 256) {
        int g = e >> 6, ic = e & 63;
        int py = (g >> 4) - 1, px = (g & 15) - 1;
        if ((unsigned)py < 14u && (unsigned)px < 14u) {
            float fyv = (y1n + (y2n-y1n)*(py*(1.f/13.f)))*15.f;
            float fxv = (x1n + (x2n-x1n)*(px*(1.f/13.f)))*15.f;
            int y0 = min(max((int)floorf(fyv),0),15), y1i = min(y0+1,15);
            int x0 = min(max((int)floorf(fxv),0),15), x1i = min(x0+1,15);
            float wy = fyv - (float)y0, wx = fxv - (float)x0;
            const float* fc = feat + ic*256;
            float top = fc[y0*16+x0]*(1.f-wx) + fc[y0*16+x1i]*wx;
            float bot = fc[y1i*16+x0]*(1.f-wx) + fc[y1i*16+x1i]*wx;
            crop[g*72 + ic] = f2bf(top*(1.f-wy) + bot*wy);
        }
    }
    __syncthreads();

    int wave = threadIdx.x >> 6, lane = threadIdx.x & 63;
    int quad = lane >> 4, l15 = lane & 15;
    int oc = wave*16 + l15;
    float biasv = b_m1[oc];
    f32x4 acc[13];
    #pragma unroll
    for (int t = 0; t < 13; ++t) acc[t] = (f32x4){biasv, biasv, biasv, biasv};

    // per-pixel-tile grid row (halo coords); pad pixels -> zero row 272
    int prow[13];
    #pragma unroll
    for (int pt = 0; pt < 13; ++pt) {
        int pix = pt*16 + l15;
        int py = pix / 14, px = pix - py*14;
        prow[pt] = (pix < 196) ? ((py+1)*16 + px + 1) : 272;
    }

    const u16* wb_oc = wbt + oc*64;
    for (int tap = 0; tap < 9; ++tap) {
        int doff = (tap/3 - 1)*16 + (tap%3 - 1);
        bf16x8 b0 = *(const bf16x8*)(wb_oc + tap*4096 +      quad*8);
        bf16x8 b1 = *(const bf16x8*)(wb_oc + tap*4096 + 32 + quad*8);
        #pragma unroll
        for (int pt = 0; pt < 13; ++pt) {
            int base = (prow[pt] + doff)*72 + quad*8;
            bf16x8 a0 = *(const bf16x8*)(crop + base);
            bf16x8 a1 = *(const bf16x8*)(crop + base + 32);
            acc[pt] = __builtin_amdgcn_mfma_f32_16x16x32_bf16(a0, b0, acc[pt], 0, 0, 0);
            acc[pt] = __builtin_amdgcn_mfma_f32_16x16x32_bf16(a1, b1, acc[pt], 0, 0, 0);
        }
    }

    // epilogue: relu * w_m2[oc], reduce over the 16 oc lanes of this wave's tile
    float wm2v = w_m2[oc];
    #pragma unroll
    for (int pt = 0; pt < 13; ++pt) {
        #pragma unroll
        for (int r = 0; r < 4; ++r) {
            float s = fmaxf(acc[pt][r], 0.f) * wm2v;
            s += __shfl_xor(s, 1);
            s += __shfl_xor(s, 2);
            s += __shfl_xor(s, 4);
            s += __shfl_xor(s, 8);
            if (l15 == 0) part[wave*208 + pt*16 + quad*4 + r] = s;
        }
    }
    __syncthreads();
    for (int t = threadIdx.x; t < 196; t += 256)
        masks_out[(size_t)n*196 + t] = part[t] + part[208+t] + part[416+t] + part[624+t] + b_m2[0];
}

// ============================================================
// final outputs
// ============================================================
__global__ void finalize(const u64* __restrict__ remw2,
    const int* __restrict__ order2, const int* __restrict__ validat,
    const float4* __restrict__ dets, const float* __restrict__ dscores,
    const float* __restrict__ masks_in, float* __restrict__ fdets,
    float* __restrict__ fscores, float* __restrict__ fmasks, float* __restrict__ keep2out)
{
    int j = blockIdx.x;
    int t = threadIdx.x;
    int o = order2[j];
    int kb = (int)((remw2[j>>6] >> (j&63)) & 1ULL);
    int k2 = kb & validat[o];
    if (t == 0) {
        float4 d = dets[o];
        if (!k2) d = make_float4(0.f,0.f,0.f,0.f);
        fdets[j*4+0]=d.x; fdets[j*4+1]=d.y; fdets[j*4+2]=d.z; fdets[j*4+3]=d.w;
        fscores[j] = k2 ? dscores[o] : 0.f;
        keep2out[j] = (float)k2;
    }
    if (t < 196) {
        float mv = masks_in[(size_t)o*196 + t];
        float sg = 1.f/(1.f + expf(-mv));
        fmasks[(size_t)j*196 + t] = k2 ? sg : 0.f;
    }
}

// ============================================================
extern "C" void kernel_launch(void* const* d_in, const int* in_sizes, int n_in,
                              void* d_out, int out_size, void* d_ws, size_t ws_size,
                              hipStream_t stream)
{
    const float* x      = (const float*)d_in[0];
    const float* w_bb   = (const float*)d_in[1];
    const float* b_bb   = (const float*)d_in[2];
    const float* w_rpn  = (const float*)d_in[3];
    const float* b_rpn  = (const float*)d_in[4];
    const float* w_cls  = (const float*)d_in[5];
    const float* b_cls  = (const float*)d_in[6];
    const float* w_box  = (const float*)d_in[7];
    const float* b_box  = (const float*)d_in[8];
    const float* w_fc1  = (const float*)d_in[9];
    const float* b_fc1  = (const float*)d_in[10];
    const float* w_fc2  = (const float*)d_in[11];
    const float* b_fc2  = (const float*)d_in[12];
    const float* w_rcls = (const float*)d_in[13];
    const float* b_rcls = (const float*)d_in[14];
    const float* w_rbox = (const float*)d_in[15];
    const float* b_rbox = (const float*)d_in[16];
    const float* w_m1   = (const float*)d_in[17];
    const float* b_m1   = (const float*)d_in[18];
    const float* w_m2   = (const float*)d_in[19];
    const float* b_m2   = (const float*)d_in[20];

    float* out = (float*)d_out;

    // ---- workspace carve-up (256B-aligned chunks) ----
    char* base = (char*)d_ws;
    auto alloc = [&](size_t bytes) { char* q = base; base += (bytes + 255) & ~(size_t)255; return q; };
    float* feat    = (float*)alloc(16384*4);
    float* hbuf    = (float*)alloc(16384*4);
    float* scores  = (float*)alloc(2304*4);
    float* boxes   = (float*)alloc(9216*4);
    int*   order1  = (int*)  alloc(2304*4);
    float* sboxes  = (float*)alloc(9216*4);
    float* sareas  = (float*)alloc(2304*4);
    u64*   supm1   = (u64*)  alloc((size_t)(N_ANCH+16)*W1*8);
    u64*   remw1   = (u64*)  alloc(W1*8);
    int*   validat = (int*)  alloc(NP*4);
    float* propws  = (float*)alloc(NP*4*4);
    u16*   wbt     = (u16*)  alloc(36864*2);
    float* flat    = (float*)alloc((size_t)NP*3136*4);
    float* h1      = (float*)alloc((size_t)NP*512*4);
    float* h2      = (float*)alloc((size_t)NP*512*4);
    float* dets    = (float*)alloc(NP*4*4);
    float* dscores = (float*)alloc(NP*4);
    float* s2      = (float*)alloc(NP*4);
    int*   order2  = (int*)  alloc(NP*4);
    float* sdets   = (float*)alloc(NP*4*4);
    float* sareas2 = (float*)alloc(NP*4);
    u64*   supm2   = (u64*)  alloc((size_t)(NP+16)*W2*8);
    u64*   remw2   = (u64*)  alloc(W2*8);

    // ---- stage 1: backbone + rpn ----
    bb_conv<<<64, 256, 0, stream>>>(x, w_bb, b_bb, feat);
    rpn_conv<<<64, 256, 0, stream>>>(feat, w_rpn, b_rpn, hbuf);
    heads_rpn<<<9, 256, 0, stream>>>(hbuf, w_cls, b_cls, w_box, b_box,
        out + O_RPN_LOGITS, out + O_RPN_DELTAS, out + O_ANCHORS, scores, boxes);

    // ---- NMS 1 ----
    sort_rank<<<9, 256, 0, stream>>>(scores, order1, N_ANCH);
    gather_sorted<<<9, 256, 0, stream>>>((const float4*)boxes, order1,
                                         (float4*)sboxes, sareas, N_ANCH);
    iou_mask<<<(N_ANCH*W1+255)/256, 256, 0, stream>>>((const float4*)sboxes, sareas,
                                                      N_ANCH, W1, 0.5f, supm1);
    nms_scan<<<1, 64, 0, stream>>>(supm1, N_ANCH, W1, remw1);
    select_props<<<1, 256, 0, stream>>>(remw1, (const float4*)sboxes,
                                        out + O_PROPOSALS, (float4*)propws, validat);

    // ---- RoI head ----
    prep_wbt<<<144, 256, 0, stream>>>(w_m1, wbt);
    pool_flat<<<NP, 256, 0, stream>>>(feat, (const float4*)propws, flat);
    gemm_bias_act<<<dim3(32, 8), 256, 0, stream>>>(flat, w_fc1, b_fc1, h1, NP, 512, 3136, 1);
    gemm_bias_act<<<dim3(32, 8), 256, 0, stream>>>(h1, w_fc2, b_fc2, h2, NP, 512, 512, 1);
    rcnn_heads<<<8, 256, 0, stream>>>(h2, w_rcls, b_rcls, w_rbox, b_rbox,
        (const float4*)propws, validat, out + O_RCNN_LOGITS, out + O_RCNN_DELTAS,
        (float4*)dets, dscores, s2);
    mask_head_mfma<<<NP, 256, 0, stream>>>(feat, (const float4*)propws, wbt, b_m1, w_m2, b_m2,
                                           out + O_RCNN_MASKS);

    // ---- NMS 2 + finalize ----
    sort_rank<<<8, 256, 0, stream>>>(s2, order2, NP);
    gather_sorted<<<8, 256, 0, stream>>>((const float4*)dets, order2,
                                         (float4*)sdets, sareas2, NP);
    iou_mask<<<(NP*W2+255)/256, 256, 0, stream>>>((const float4*)sdets, sareas2,
                                                  NP, W2, 0.3f, supm2);
    nms_scan<<<1, 64, 0, stream>>>(supm2, NP, W2, remw2);
    finalize<<<NP, 256, 0, stream>>>(remw2, order2, validat, (const float4*)dets,
        dscores, out + O_RCNN_MASKS, out + O_FINAL_DETS, out + O_FINAL_SCORES,
        out + O_FINAL_MASKS, out + O_KEEP2);
}

// Round 4
// 1043.077 us; speedup vs baseline: 1.9134x; 1.2343x over previous
//
#include <hip/hip_runtime.h>
#include <math.h>

typedef unsigned long long u64;
typedef unsigned short u16;
typedef __attribute__((ext_vector_type(8))) short bf16x8;
typedef __attribute__((ext_vector_type(4))) float f32x4;

#define N_ANCH 2304
#define NP     2000
#define W1     36   // 2304/64
#define W2     32   // ceil(2000/64)

// ---------- output offsets (floats) ----------
#define O_RPN_LOGITS   0
#define O_RPN_DELTAS   4608
#define O_PROPOSALS    13824
#define O_ANCHORS      21824
#define O_RCNN_LOGITS  31040
#define O_RCNN_DELTAS  35040
#define O_RCNN_MASKS   43040
#define O_FINAL_DETS   435040
#define O_FINAL_MASKS  443040
#define O_FINAL_SCORES 835040
#define O_KEEP2        837040

__device__ __forceinline__ u16 f2bf(float f) {
    unsigned int x = __float_as_uint(f);
    unsigned int r = x + 0x7fffu + ((x >> 16) & 1u);   // RTNE
    return (u16)(r >> 16);
}

// ============================================================
// K1: backbone conv + relu -> feat [64,16,16] and feat_tf [pix][64]
// ============================================================
__global__ __launch_bounds__(256) void bb_conv(const float* __restrict__ x,
    const float* __restrict__ w, const float* __restrict__ b,
    float* __restrict__ feat, float* __restrict__ feat_tf)
{
    __shared__ float ws_[768];
    int c = blockIdx.x;
    for (int e = threadIdx.x; e < 768; e += 256) ws_[e] = w[c*768 + e];
    __syncthreads();
    int fy = threadIdx.x >> 4, fx = threadIdx.x & 15;
    float acc = b[c];
    for (int ic = 0; ic < 3; ++ic)
        for (int ky = 0; ky < 16; ++ky) {
            const float* xr = x + (size_t)(ic*256 + fy*16+ky)*256 + fx*16;
            const float* wr = ws_ + ic*256 + ky*16;
            #pragma unroll
            for (int kx = 0; kx < 16; ++kx) acc += xr[kx]*wr[kx];
        }
    float v = fmaxf(acc, 0.f);
    feat[c*256 + threadIdx.x] = v;
    feat_tf[threadIdx.x*64 + c] = v;
}

// ============================================================
// K2: RPN 3x3 SAME conv + relu -> h [64,16,16]
// ============================================================
__global__ __launch_bounds__(256) void rpn_conv(const float* __restrict__ feat,
    const float* __restrict__ w, const float* __restrict__ b, float* __restrict__ h)
{
    __shared__ float f[16384];
    __shared__ float ws_[576];
    int c = blockIdx.x;
    for (int e = threadIdx.x; e < 16384; e += 256) f[e] = feat[e];
    for (int e = threadIdx.x; e < 576; e += 256) ws_[e] = w[c*576 + e];
    __syncthreads();
    int fy = threadIdx.x >> 4, fx = threadIdx.x & 15;
    float acc = b[c];
    for (int ic = 0; ic < 64; ++ic) {
        const float* fc = f + ic*256;
        const float* wc = ws_ + ic*9;
        #pragma unroll
        for (int dy = 0; dy < 3; ++dy) {
            int y = fy + dy - 1;
            if (y < 0 || y > 15) continue;
            #pragma unroll
            for (int dx = 0; dx < 3; ++dx) {
                int xx = fx + dx - 1;
                if (xx < 0 || xx > 15) continue;
                acc += fc[y*16+xx]*wc[dy*3+dx];
            }
        }
    }
    h[c*256 + threadIdx.x] = fmaxf(acc, 0.f);
}

// ============================================================
// K3: RPN heads (1x1 convs) + softmax + anchors + decode + clip
// ============================================================
__global__ __launch_bounds__(256) void heads_rpn(const float* __restrict__ hbuf,
    const float* __restrict__ w_cls, const float* __restrict__ b_cls,
    const float* __restrict__ w_box, const float* __restrict__ b_box,
    float* __restrict__ out_logits, float* __restrict__ out_deltas,
    float* __restrict__ out_anchors,
    float* __restrict__ scores, float* __restrict__ boxes)
{
    int idx = blockIdx.x*256 + threadIdx.x;
    if (idx >= N_ANCH) return;
    int fy = idx / 144, r = idx % 144, fx = r / 9, a = r % 9;
    int pix = fy*16 + fx;
    float l0 = b_cls[a*2+0], l1 = b_cls[a*2+1];
    float d0 = b_box[a*4+0], d1 = b_box[a*4+1], d2 = b_box[a*4+2], d3 = b_box[a*4+3];
    const float* wc0 = w_cls + (a*2+0)*64;
    const float* wc1 = w_cls + (a*2+1)*64;
    const float* wb0 = w_box + (a*4+0)*64;
    const float* wb1 = w_box + (a*4+1)*64;
    const float* wb2 = w_box + (a*4+2)*64;
    const float* wb3 = w_box + (a*4+3)*64;
    for (int c = 0; c < 64; ++c) {
        float hv = hbuf[c*256 + pix];
        l0 += hv*wc0[c]; l1 += hv*wc1[c];
        d0 += hv*wb0[c]; d1 += hv*wb1[c]; d2 += hv*wb2[c]; d3 += hv*wb3[c];
    }
    out_logits[idx*2+0] = l0; out_logits[idx*2+1] = l1;
    out_deltas[idx*4+0] = d0; out_deltas[idx*4+1] = d1;
    out_deltas[idx*4+2] = d2; out_deltas[idx*4+3] = d3;
    float mx = fmaxf(l0,l1);
    float e0 = expf(l0-mx), e1 = expf(l1-mx);
    scores[idx] = e1/(e0+e1);
    float SC = (a/3 == 0) ? 32.f : ((a/3 == 1) ? 64.f : 128.f);
    float RT = (a%3 == 0) ? 0.5f : ((a%3 == 1) ? 1.f : 2.f);
    float wsz = SC*sqrtf(RT), hsz = SC/sqrtf(RT);
    float cx = (fx+0.5f)*16.f, cy = (fy+0.5f)*16.f;
    float ax1 = cx - wsz*0.5f, ay1 = cy - hsz*0.5f;
    float ax2 = cx + wsz*0.5f, ay2 = cy + hsz*0.5f;
    out_anchors[idx*4+0]=ax1; out_anchors[idx*4+1]=ay1;
    out_anchors[idx*4+2]=ax2; out_anchors[idx*4+3]=ay2;
    float aw = ax2-ax1, ah = ay2-ay1;
    float acx = ax1 + 0.5f*aw, acy = ay1 + 0.5f*ah;
    float ncx = acx + d0*aw, ncy = acy + d1*ah;
    float nw = aw*expf(d2), nh = ah*expf(d3);
    float x1 = ncx - 0.5f*nw, y1 = ncy - 0.5f*nh;
    float x2 = ncx + 0.5f*nw, y2 = ncy + 0.5f*nh;
    const float lim = 255.f;
    x1 = fminf(fmaxf(x1,0.f),lim); y1 = fminf(fmaxf(y1,0.f),lim);
    x2 = fminf(fmaxf(x2,0.f),lim); y2 = fminf(fmaxf(y2,0.f),lim);
    boxes[idx*4+0]=x1; boxes[idx*4+1]=y1; boxes[idx*4+2]=x2; boxes[idx*4+3]=y2;
}

// ============================================================
// stable descending argsort by rank counting (matches jnp.argsort(-s))
// ============================================================
__global__ __launch_bounds__(256) void sort_rank(const float* __restrict__ score,
                                                 int* __restrict__ order, int n)
{
    __shared__ float sc[2304];
    for (int i = threadIdx.x; i < n; i += 256) sc[i] = score[i];
    __syncthreads();
    int i = blockIdx.x*256 + threadIdx.x;
    if (i >= n) return;
    float si = sc[i];
    int r = 0;
    for (int j = 0; j < n; ++j) {
        float sj = sc[j];
        r += (sj > si) || (sj == si && j < i);
    }
    order[r] = i;
}

__global__ __launch_bounds__(256) void gather_sorted(const float4* __restrict__ boxes,
    const int* __restrict__ order, float4* __restrict__ sb, float* __restrict__ sa, int n)
{
    int i = blockIdx.x*256 + threadIdx.x;
    if (i >= n) return;
    float4 b = boxes[order[i]];
    sb[i] = b;
    sa[i] = fmaxf(b.z-b.x, 0.f)*fmaxf(b.w-b.y, 0.f);
}

// ============================================================
// IoU suppression bitmask (bits only for j > i)
// ============================================================
__global__ __launch_bounds__(256) void iou_mask(const float4* __restrict__ sb,
    const float* __restrict__ sa, int n, int words, float thr, u64* __restrict__ mask)
{
    int gid = blockIdx.x*256 + threadIdx.x;
    if (gid >= n*words) return;
    int i = gid / words, w = gid % words;
    float4 bi = sb[i]; float ai = sa[i];
    u64 m = 0;
    int j0 = w*64;
    for (int bb = 0; bb < 64; ++bb) {
        int j = j0 + bb;
        if (j > i && j < n) {
            float4 bj = sb[j];
            float xx1 = fmaxf(bi.x, bj.x), yy1 = fmaxf(bi.y, bj.y);
            float xx2 = fminf(bi.z, bj.z), yy2 = fminf(bi.w, bj.w);
            float inter = fmaxf(xx2-xx1, 0.f)*fmaxf(yy2-yy1, 0.f);
            float iou = inter / (ai + sa[j] - inter + 1e-8f);
            if (iou > thr) m |= 1ULL << bb;
        }
    }
    mask[(size_t)i*words + w] = m;
}

// ============================================================
// single-wave greedy scan, software-pipelined (prefetch depth 16)
// ============================================================
__global__ void nms_scan(const u64* __restrict__ mask, int n, int words, u64* __restrict__ remout)
{
    int lane = threadIdx.x;
    bool act = lane < words;
    const u64* mrow = mask + lane;
    u64 pre[16];
    #pragma unroll
    for (int d = 0; d < 16; ++d)
        pre[d] = act ? mrow[(size_t)d*words] : 0;
    u64 rem = ~0ULL;
    u64 cur = 0;
    for (int i0 = 0; i0 < n; i0 += 16) {
        int w = i0 >> 6;
        if ((i0 & 63) == 0) cur = __shfl(rem, w);
        #pragma unroll
        for (int d = 0; d < 16; ++d) {
            int i = i0 + d;
            u64 row = pre[d];
            pre[d] = act ? mrow[(size_t)(i+16)*words] : 0;  // prefetch (slack rows)
            u64 sw = __shfl(row, w);
            bool alive = (cur >> (i & 63)) & 1ULL;
            rem &= alive ? ~row : ~0ULL;
            cur &= alive ? ~sw : ~0ULL;
        }
    }
    if (act) remout[lane] = rem;
}

// ============================================================
// kept-first stable selection -> proposals / valid
// ============================================================
__global__ __launch_bounds__(256) void select_props(const u64* __restrict__ remw,
    const float4* __restrict__ sboxes, float* __restrict__ prop_out,
    float4* __restrict__ propws, int* __restrict__ validat)
{
    __shared__ int cnt[256];
    __shared__ int pref[257];
    int t = threadIdx.x;
    int base = t*9;
    int c = 0;
    #pragma unroll
    for (int q = 0; q < 9; ++q) { int i = base+q; c += (int)((remw[i>>6]>>(i&63))&1ULL); }
    cnt[t] = c; __syncthreads();
    if (t == 0) { pref[0]=0; for (int u=0;u<256;u++) pref[u+1]=pref[u]+cnt[u]; }
    __syncthreads();
    int K = pref[256];
    int kb = pref[t];
    int nb = K + (base - pref[t]);
    for (int q = 0; q < 9; ++q) {
        int i = base + q;
        int k = (int)((remw[i>>6]>>(i&63))&1ULL);
        int pos = k ? kb : nb;
        if (k) kb++; else nb++;
        if (pos < NP) {
            validat[pos] = k;
            float4 p = k ? sboxes[i] : make_float4(0.f,0.f,0.f,0.f);
            propws[pos] = p;
            prop_out[pos*4+0]=p.x; prop_out[pos*4+1]=p.y;
            prop_out[pos*4+2]=p.z; prop_out[pos*4+3]=p.w;
        }
    }
}

// ============================================================
// weight prep for MFMA mask conv: wbt[tap][oc][ic] (bf16)
// ============================================================
__global__ __launch_bounds__(256) void prep_wbt(const float* __restrict__ w, u16* __restrict__ wbt)
{
    int e = blockIdx.x*256 + threadIdx.x;
    if (e >= 36864) return;
    int oc = e / 576, rem = e % 576, ic = rem / 9, tap = rem % 9;
    wbt[tap*4096 + oc*64 + ic] = f2bf(w[e]);
}

// ============================================================
// K6: crop_resize + 2x2 maxpool -> flat [2000][3136] f32
// coalesced reads from feat_tf [pix][64]; values bit-identical to R2 pool
// ============================================================
__global__ __launch_bounds__(256) void pool_flat(const float* __restrict__ feat_tf,
    const float4* __restrict__ propws, float* __restrict__ flat)
{
    __shared__ int4   cp[196];
    __shared__ float2 cw[196];
    __shared__ float  pooled[3136];
    int n = blockIdx.x;
    int t = threadIdx.x;
    float4 p = propws[n];
    float x1n = p.x*(1.f/255.f), y1n = p.y*(1.f/255.f);
    float x2n = p.z*(1.f/255.f), y2n = p.w*(1.f/255.f);
    if (t < 196) {
        int py = t / 14, px = t % 14;
        float fyv = (y1n + (y2n-y1n)*(py*(1.f/13.f)))*15.f;
        float fxv = (x1n + (x2n-x1n)*(px*(1.f/13.f)))*15.f;
        int y0 = min(max((int)floorf(fyv),0),15), y1i = min(y0+1,15);
        int x0 = min(max((int)floorf(fxv),0),15), x1i = min(x0+1,15);
        cp[t] = make_int4(y0*16+x0, y0*16+x1i, y1i*16+x0, y1i*16+x1i);
        cw[t] = make_float2(fyv - (float)y0, fxv - (float)x0);
    }
    __syncthreads();
    int wave = t >> 6, lane = t & 63;
    for (int it = 0; it < 13; ++it) {
        int q = it*4 + wave;
        if (q < 49) {
            int qy = q / 7, qx = q % 7;
            int c00 = (2*qy)*14 + 2*qx;
            float mx = -1e30f;
            int cells[4] = {c00, c00+1, c00+14, c00+15};
            #pragma unroll
            for (int s = 0; s < 4; ++s) {
                int4 pp = cp[cells[s]];
                float2 ww = cw[cells[s]];
                float v00 = feat_tf[pp.x*64 + lane];
                float v01 = feat_tf[pp.y*64 + lane];
                float v10 = feat_tf[pp.z*64 + lane];
                float v11 = feat_tf[pp.w*64 + lane];
                float top = v00*(1.f-ww.y) + v01*ww.y;
                float bot = v10*(1.f-ww.y) + v11*ww.y;
                mx = fmaxf(mx, top*(1.f-ww.x) + bot*ww.x);
            }
            pooled[lane*49 + q] = mx;
        }
    }
    __syncthreads();
    size_t rowoff = (size_t)n*3136;
    for (int k = t; k < 3136; k += 256) flat[rowoff + k] = pooled[k];
}

// ============================================================
// f32 GEMM, bit-identical accumulation to the R2 passing kernel:
// single accumulator per output, fmaf over strictly ascending k.
// Tile 32(M)x64(N), BK=32, 128 threads (2 waves), grid (63, N/64)
//  -> 504 blocks for fc1/fc2 (2 blocks/CU).
// ============================================================
__global__ __launch_bounds__(128) void gemm_f32(const float* __restrict__ A,
    const float* __restrict__ B, const float* __restrict__ bias, float* __restrict__ C,
    int M, int N, int K, int relu)
{
    __shared__ float As[32][36];   // [k][row], padded (row of 144B, 16B aligned)
    __shared__ float Bs[32][68];   // [k][col], padded (row of 272B, 16B aligned)
    int row0 = blockIdx.x*32, col0 = blockIdx.y*64;
    int t = threadIdx.x;
    int tx = t & 15, ty = t >> 4;  // tx: 16 col-groups, ty: 8 row-groups
    float acc[4][4] = {};
    for (int k0 = 0; k0 < K; k0 += 32) {
        #pragma unroll
        for (int u = 0; u < 2; ++u) {          // stage A: 32 rows x 32 k
            int idx = t + u*128;               // 0..255
            int r = idx >> 3;                  // 0..31
            int kq = (idx & 7)*4;              // 0..28
            int gm = row0 + r;
            float4 v = make_float4(0.f,0.f,0.f,0.f);
            if (gm < M) v = *(const float4*)(A + (size_t)gm*K + k0 + kq);
            As[kq+0][r]=v.x; As[kq+1][r]=v.y; As[kq+2][r]=v.z; As[kq+3][r]=v.w;
        }
        #pragma unroll
        for (int u = 0; u < 4; ++u) {          // stage B: 32 k x 64 cols
            int idx = t + u*128;               // 0..511
            int kr = idx >> 4;                 // 0..31
            int cq = (idx & 15)*4;
            *(float4*)&Bs[kr][cq] = *(const float4*)(B + (size_t)(k0+kr)*N + col0 + cq);
        }
        __syncthreads();
        #pragma unroll
        for (int k = 0; k < 32; ++k) {
            float4 av = *(float4*)&As[k][ty*4];
            float4 bv = *(float4*)&Bs[k][tx*4];
            float a_[4] = {av.x, av.y, av.z, av.w};
            float b_[4] = {bv.x, bv.y, bv.z, bv.w};
            #pragma unroll
            for (int i = 0; i < 4; ++i)
                #pragma unroll
                for (int j = 0; j < 4; ++j)
                    acc[i][j] = fmaf(a_[i], b_[j], acc[i][j]);
        }
        __syncthreads();
    }
    #pragma unroll
    for (int i = 0; i < 4; ++i) {
        int gm = row0 + ty*4 + i;
        if (gm >= M) continue;
        #pragma unroll
        for (int j = 0; j < 4; ++j) {
            int gn = col0 + tx*4 + j;
            float v = acc[i][j] + bias[gn];
            if (relu) v = fmaxf(v, 0.f);
            C[(size_t)gm*N + gn] = v;
        }
    }
}

// ============================================================
// K9: rcnn heads — coalesced LDS staging, then 8 serial threads replay
// the R2 sequential fmaf chain bit-exactly.
// ============================================================
__global__ __launch_bounds__(256) void rcnn_heads_lds(const float* __restrict__ h2,
    const float* __restrict__ w_rcls, const float* __restrict__ b_rcls,
    const float* __restrict__ w_rbox, const float* __restrict__ b_rbox,
    const float4* __restrict__ propws, const int* __restrict__ validat,
    float* __restrict__ out_logits, float* __restrict__ out_deltas,
    float4* __restrict__ dets, float* __restrict__ dscores, float* __restrict__ s2)
{
    __shared__ float hs[8*520];    // stride 520 -> 8 serial readers hit 8 banks
    int b0 = blockIdx.x*8;
    for (int e = threadIdx.x; e < 8*512; e += 256) {
        int pr = e >> 9, k = e & 511;
        hs[pr*520 + k] = h2[(size_t)(b0+pr)*512 + k];
    }
    __syncthreads();
    int t = threadIdx.x;
    if (t >= 8) return;
    int n = b0 + t;
    const float* hv = hs + t*520;
    float l0 = b_rcls[0], l1 = b_rcls[1];
    float d0 = b_rbox[0], d1 = b_rbox[1], d2 = b_rbox[2], d3 = b_rbox[3];
    for (int k = 0; k < 512; ++k) {
        float v = hv[k];
        l0 = fmaf(v, w_rcls[k*2+0], l0); l1 = fmaf(v, w_rcls[k*2+1], l1);
        d0 = fmaf(v, w_rbox[k*4+0], d0); d1 = fmaf(v, w_rbox[k*4+1], d1);
        d2 = fmaf(v, w_rbox[k*4+2], d2); d3 = fmaf(v, w_rbox[k*4+3], d3);
    }
    out_logits[n*2+0]=l0; out_logits[n*2+1]=l1;
    out_deltas[n*4+0]=d0; out_deltas[n*4+1]=d1;
    out_deltas[n*4+2]=d2; out_deltas[n*4+3]=d3;
    float mx = fmaxf(l0,l1);
    float e0 = expf(l0-mx), e1 = expf(l1-mx);
    float sc = e1/(e0+e1);
    float4 p = propws[n];
    float w = p.z-p.x, h = p.w-p.y;
    float cx = p.x + 0.5f*w, cy = p.y + 0.5f*h;
    float ncx = cx + d0*w, ncy = cy + d1*h;
    float nw = w*expf(d2), nh = h*expf(d3);
    float x1 = ncx-0.5f*nw, y1 = ncy-0.5f*nh, x2 = ncx+0.5f*nw, y2 = ncy+0.5f*nh;
    const float lim = 255.f;
    x1 = fminf(fmaxf(x1,0.f),lim); y1 = fminf(fmaxf(y1,0.f),lim);
    x2 = fminf(fmaxf(x2,0.f),lim); y2 = fminf(fmaxf(y2,0.f),lim);
    dets[n] = make_float4(x1,y1,x2,y2);
    dscores[n] = sc;
    s2[n] = validat[n] ? sc : -1.0f;
}

// ============================================================
// K10: MFMA mask head, coalesced staging from feat_tf [pix][64]
// ============================================================
__global__ __launch_bounds__(256) void mask_head_mfma(const float* __restrict__ feat_tf,
    const float4* __restrict__ propws, const u16* __restrict__ wbt,
    const float* __restrict__ b_m1, const float* __restrict__ w_m2,
    const float* __restrict__ b_m2, float* __restrict__ masks_out)
{
    __shared__ __align__(16) u16 crop[292*72];
    __shared__ float part[4*208];
    __shared__ int4   cp[256];
    __shared__ float2 cw[256];
    int n = blockIdx.x;
    int t = threadIdx.x;
    float4 p = propws[n];
    float x1n = p.x*(1.f/255.f), y1n = p.y*(1.f/255.f);
    float x2n = p.z*(1.f/255.f), y2n = p.w*(1.f/255.f);
    {
        int g = t;
        int py = (g >> 4) - 1, px = (g & 15) - 1;
        if ((unsigned)py < 14u && (unsigned)px < 14u) {
            float fyv = (y1n + (y2n-y1n)*(py*(1.f/13.f)))*15.f;
            float fxv = (x1n + (x2n-x1n)*(px*(1.f/13.f)))*15.f;
            int y0 = min(max((int)floorf(fyv),0),15), y1i = min(y0+1,15);
            int x0 = min(max((int)floorf(fxv),0),15), x1i = min(x0+1,15);
            cp[g] = make_int4(y0*16+x0, y0*16+x1i, y1i*16+x0, y1i*16+x1i);
            cw[g] = make_float2(fyv - (float)y0, fxv - (float)x0);
        } else {
            cp[g] = make_int4(-1,-1,-1,-1);
        }
        for (int e = 256*72 + t; e < 292*72; e += 256) crop[e] = 0;
    }
    __syncthreads();
    int wave = t >> 6, lane = t & 63;
    for (int it = 0; it < 64; ++it) {
        int g = it*4 + wave;
        int4 pp = cp[g];
        u16 ov = 0;
        if (pp.x >= 0) {
            float2 ww = cw[g];
            float v00 = feat_tf[pp.x*64 + lane];
            float v01 = feat_tf[pp.y*64 + lane];
            float v10 = feat_tf[pp.z*64 + lane];
            float v11 = feat_tf[pp.w*64 + lane];
            float top = v00*(1.f-ww.y) + v01*ww.y;
            float bot = v10*(1.f-ww.y) + v11*ww.y;
            ov = f2bf(top*(1.f-ww.x) + bot*ww.x);
        }
        crop[g*72 + lane] = ov;
    }
    __syncthreads();

    int quad = lane >> 4, l15 = lane & 15;
    int oc = wave*16 + l15;
    float biasv = b_m1[oc];
    f32x4 acc[13];
    #pragma unroll
    for (int pt = 0; pt < 13; ++pt) acc[pt] = (f32x4){biasv, biasv, biasv, biasv};

    int prow[13];
    #pragma unroll
    for (int pt = 0; pt < 13; ++pt) {
        int pix = pt*16 + l15;
        int py = pix / 14, px = pix - py*14;
        prow[pt] = (pix < 196) ? ((py+1)*16 + px + 1) : 272;
    }

    const u16* wb_oc = wbt + oc*64;
    for (int tap = 0; tap < 9; ++tap) {
        int doff = (tap/3 - 1)*16 + (tap%3 - 1);
        bf16x8 b0 = *(const bf16x8*)(wb_oc + tap*4096 +      quad*8);
        bf16x8 b1 = *(const bf16x8*)(wb_oc + tap*4096 + 32 + quad*8);
        #pragma unroll
        for (int pt = 0; pt < 13; ++pt) {
            int base = (prow[pt] + doff)*72 + quad*8;
            bf16x8 a0 = *(const bf16x8*)(crop + base);
            bf16x8 a1 = *(const bf16x8*)(crop + base + 32);
            acc[pt] = __builtin_amdgcn_mfma_f32_16x16x32_bf16(a0, b0, acc[pt], 0, 0, 0);
            acc[pt] = __builtin_amdgcn_mfma_f32_16x16x32_bf16(a1, b1, acc[pt], 0, 0, 0);
        }
    }

    float wm2v = w_m2[oc];
    #pragma unroll
    for (int pt = 0; pt < 13; ++pt) {
        #pragma unroll
        for (int r = 0; r < 4; ++r) {
            float s = fmaxf(acc[pt][r], 0.f) * wm2v;
            s += __shfl_xor(s, 1);
            s += __shfl_xor(s, 2);
            s += __shfl_xor(s, 4);
            s += __shfl_xor(s, 8);
            if (l15 == 0) part[wave*208 + pt*16 + quad*4 + r] = s;
        }
    }
    __syncthreads();
    for (int tt = t; tt < 196; tt += 256)
        masks_out[(size_t)n*196 + tt] = part[tt] + part[208+tt] + part[416+tt] + part[624+tt] + b_m2[0];
}

// ============================================================
// final outputs
// ============================================================
__global__ void finalize(const u64* __restrict__ remw2,
    const int* __restrict__ order2, const int* __restrict__ validat,
    const float4* __restrict__ dets, const float* __restrict__ dscores,
    const float* __restrict__ masks_in, float* __restrict__ fdets,
    float* __restrict__ fscores, float* __restrict__ fmasks, float* __restrict__ keep2out)
{
    int j = blockIdx.x;
    int t = threadIdx.x;
    int o = order2[j];
    int kb = (int)((remw2[j>>6] >> (j&63)) & 1ULL);
    int k2 = kb & validat[o];
    if (t == 0) {
        float4 d = dets[o];
        if (!k2) d = make_float4(0.f,0.f,0.f,0.f);
        fdets[j*4+0]=d.x; fdets[j*4+1]=d.y; fdets[j*4+2]=d.z; fdets[j*4+3]=d.w;
        fscores[j] = k2 ? dscores[o] : 0.f;
        keep2out[j] = (float)k2;
    }
    if (t < 196) {
        float mv = masks_in[(size_t)o*196 + t];
        float sg = 1.f/(1.f + expf(-mv));
        fmasks[(size_t)j*196 + t] = k2 ? sg : 0.f;
    }
}

// ============================================================
extern "C" void kernel_launch(void* const* d_in, const int* in_sizes, int n_in,
                              void* d_out, int out_size, void* d_ws, size_t ws_size,
                              hipStream_t stream)
{
    const float* x      = (const float*)d_in[0];
    const float* w_bb   = (const float*)d_in[1];
    const float* b_bb   = (const float*)d_in[2];
    const float* w_rpn  = (const float*)d_in[3];
    const float* b_rpn  = (const float*)d_in[4];
    const float* w_cls  = (const float*)d_in[5];
    const float* b_cls  = (const float*)d_in[6];
    const float* w_box  = (const float*)d_in[7];
    const float* b_box  = (const float*)d_in[8];
    const float* w_fc1  = (const float*)d_in[9];
    const float* b_fc1  = (const float*)d_in[10];
    const float* w_fc2  = (const float*)d_in[11];
    const float* b_fc2  = (const float*)d_in[12];
    const float* w_rcls = (const float*)d_in[13];
    const float* b_rcls = (const float*)d_in[14];
    const float* w_rbox = (const float*)d_in[15];
    const float* b_rbox = (const float*)d_in[16];
    const float* w_m1   = (const float*)d_in[17];
    const float* b_m1   = (const float*)d_in[18];
    const float* w_m2   = (const float*)d_in[19];
    const float* b_m2   = (const float*)d_in[20];

    float* out = (float*)d_out;

    // ---- workspace carve-up (256B-aligned chunks) ----
    char* basep = (char*)d_ws;
    auto alloc = [&](size_t bytes) { char* q = basep; basep += (bytes + 255) & ~(size_t)255; return q; };
    float* feat    = (float*)alloc(16384*4);
    float* feat_tf = (float*)alloc(16384*4);
    float* hbuf    = (float*)alloc(16384*4);
    float* scores  = (float*)alloc(2304*4);
    float* boxes   = (float*)alloc(9216*4);
    int*   order1  = (int*)  alloc(2304*4);
    float* sboxes  = (float*)alloc(9216*4);
    float* sareas  = (float*)alloc(2304*4);
    u64*   supm1   = (u64*)  alloc((size_t)(N_ANCH+16)*W1*8);
    u64*   remw1   = (u64*)  alloc(W1*8);
    int*   validat = (int*)  alloc(NP*4);
    float* propws  = (float*)alloc(NP*4*4);
    u16*   wbt     = (u16*)  alloc(36864*2);
    float* flat    = (float*)alloc((size_t)NP*3136*4);
    float* h1      = (float*)alloc((size_t)NP*512*4);
    float* h2      = (float*)alloc((size_t)NP*512*4);
    float* dets    = (float*)alloc(NP*4*4);
    float* dscores = (float*)alloc(NP*4);
    float* s2      = (float*)alloc(NP*4);
    int*   order2  = (int*)  alloc(NP*4);
    float* sdets   = (float*)alloc(NP*4*4);
    float* sareas2 = (float*)alloc(NP*4);
    u64*   supm2   = (u64*)  alloc((size_t)(NP+16)*W2*8);
    u64*   remw2   = (u64*)  alloc(W2*8);

    // ---- stage 1: backbone + rpn ----
    bb_conv<<<64, 256, 0, stream>>>(x, w_bb, b_bb, feat, feat_tf);
    rpn_conv<<<64, 256, 0, stream>>>(feat, w_rpn, b_rpn, hbuf);
    heads_rpn<<<9, 256, 0, stream>>>(hbuf, w_cls, b_cls, w_box, b_box,
        out + O_RPN_LOGITS, out + O_RPN_DELTAS, out + O_ANCHORS, scores, boxes);

    // ---- NMS 1 ----
    sort_rank<<<9, 256, 0, stream>>>(scores, order1, N_ANCH);
    gather_sorted<<<9, 256, 0, stream>>>((const float4*)boxes, order1,
                                         (float4*)sboxes, sareas, N_ANCH);
    iou_mask<<<(N_ANCH*W1+255)/256, 256, 0, stream>>>((const float4*)sboxes, sareas,
                                                      N_ANCH, W1, 0.5f, supm1);
    nms_scan<<<1, 64, 0, stream>>>(supm1, N_ANCH, W1, remw1);
    select_props<<<1, 256, 0, stream>>>(remw1, (const float4*)sboxes,
                                        out + O_PROPOSALS, (float4*)propws, validat);

    // ---- weight prep (independent of NMS; early) ----
    prep_wbt<<<144, 256, 0, stream>>>(w_m1, wbt);

    // ---- RoI head ----
    pool_flat<<<NP, 256, 0, stream>>>(feat_tf, (const float4*)propws, flat);
    gemm_f32<<<dim3(63, 8), 128, 0, stream>>>(flat, w_fc1, b_fc1, h1, NP, 512, 3136, 1);
    gemm_f32<<<dim3(63, 8), 128, 0, stream>>>(h1, w_fc2, b_fc2, h2, NP, 512, 512, 1);
    rcnn_heads_lds<<<250, 256, 0, stream>>>(h2, w_rcls, b_rcls, w_rbox, b_rbox,
        (const float4*)propws, validat, out + O_RCNN_LOGITS, out + O_RCNN_DELTAS,
        (float4*)dets, dscores, s2);
    mask_head_mfma<<<NP, 256, 0, stream>>>(feat_tf, (const float4*)propws, wbt, b_m1, w_m2, b_m2,
                                           out + O_RCNN_MASKS);

    // ---- NMS 2 + finalize ----
    sort_rank<<<8, 256, 0, stream>>>(s2, order2, NP);
    gather_sorted<<<8, 256, 0, stream>>>((const float4*)dets, order2,
                                         (float4*)sdets, sareas2, NP);
    iou_mask<<<(NP*W2+255)/256, 256, 0, stream>>>((const float4*)sdets, sareas2,
                                                  NP, W2, 0.3f, supm2);
    nms_scan<<<1, 64, 0, stream>>>(supm2, NP, W2, remw2);
    finalize<<<NP, 256, 0, stream>>>(remw2, order2, validat, (const float4*)dets,
        dscores, out + O_RCNN_MASKS, out + O_FINAL_DETS, out + O_FINAL_SCORES,
        out + O_FINAL_MASKS, out + O_KEEP2);
}